// Round 1
// baseline (179.008 us; speedup 1.0000x reference)
//
#include <hip/hip_runtime.h>
#include <hip/hip_bf16.h>

typedef __attribute__((ext_vector_type(4))) float f32x4;
typedef __attribute__((ext_vector_type(8))) short bf16x8;

static constexpr int B   = 2;
static constexpr int N   = 2048;
static constexpr int F   = 64;
static constexpr int H   = 4;
static constexpr int HID = 128;
static constexpr int BN  = B * N;
static constexpr size_t LOG_SZ = (size_t)B * N * N * 3;

__device__ __forceinline__ float sigmoidf_(float x) { return 1.0f / (1.0f + __expf(-x)); }

// ------------- K1: hfeat = x @ gat_kernel ; s_self, s_neigh -------------
__global__ __launch_bounds__(128) void k_feat(
    const float* __restrict__ x, const float* __restrict__ gk,
    const float* __restrict__ asel, const float* __restrict__ anei,
    float* __restrict__ hfeat, float* __restrict__ sself, float* __restrict__ sneigh) {
  const int bn = blockIdx.x;
  const int t  = threadIdx.x;           // 0..127 = h*32+c
  __shared__ float xs[F];
  if (t < F) xs[t] = x[(size_t)bn * F + t];
  __syncthreads();
  float acc = 0.f;
  #pragma unroll 8
  for (int f = 0; f < F; ++f) acc += xs[f] * gk[f * HID + t];
  hfeat[(size_t)bn * HID + t] = acc;
  float ps = acc * asel[t];
  float pn = acc * anei[t];
  #pragma unroll
  for (int d = 16; d >= 1; d >>= 1) {
    ps += __shfl_xor(ps, d, 32);
    pn += __shfl_xor(pn, d, 32);
  }
  if ((t & 31) == 0) {
    sself [bn * H + (t >> 5)] = ps;
    sneigh[bn * H + (t >> 5)] = pn;
  }
}

// ------------- K2: sparse GAT attention (masked softmax == sparse) -------------
__global__ __launch_bounds__(256) void k_attn(
    const float* __restrict__ a, const float* __restrict__ hfeat,
    const float* __restrict__ sself, const float* __restrict__ sneigh,
    const float* __restrict__ bias, float* __restrict__ conv) {
  const int bi = blockIdx.x;            // b*N + i
  const int t  = threadIdx.x;
  const int bbase = bi & ~(N - 1);      // b*N
  __shared__ int   nbr[N];
  __shared__ float sc[H][N];
  __shared__ int   cnts[256];
  __shared__ float wred[4][H];
  __shared__ float winv[H];
  __shared__ float accbuf[HID];

  // deterministic neighbor compaction: thread t owns j in [8t, 8t+8)
  const float* arow = a + (size_t)bi * N;
  f32x4 a0 = *(const f32x4*)&arow[t * 8];
  f32x4 a1 = *(const f32x4*)&arow[t * 8 + 4];
  int mask = 0;
  #pragma unroll
  for (int q = 0; q < 4; ++q) {
    if (a0[q] > 0.5f) mask |= 1 << q;
    if (a1[q] > 0.5f) mask |= 1 << (q + 4);
  }
  const int lc = __popc(mask);
  cnts[t] = lc;
  __syncthreads();
  for (int off = 1; off < 256; off <<= 1) {   // Hillis-Steele inclusive scan
    int v = cnts[t];
    int add = (t >= off) ? cnts[t - off] : 0;
    __syncthreads();
    cnts[t] = v + add;
    __syncthreads();
  }
  const int deg = cnts[255];
  int p = cnts[t] - lc;
  #pragma unroll
  for (int q = 0; q < 8; ++q) if (mask & (1 << q)) nbr[p++] = t * 8 + q;
  __syncthreads();

  // exp(leaky(s_self[i]+s_neigh[j])) per head; scores are O(1), no max-sub needed
  float si[H];
  #pragma unroll
  for (int h = 0; h < H; ++h) si[h] = sself[bi * H + h];
  float psum[H] = {0.f, 0.f, 0.f, 0.f};
  for (int n = t; n < deg; n += 256) {
    const int j = nbr[n];
    const float* sn = sneigh + (size_t)(bbase + j) * H;
    #pragma unroll
    for (int h = 0; h < H; ++h) {
      float s = si[h] + sn[h];
      s = (s > 0.f) ? s : 0.2f * s;          // leaky_relu 0.2
      float e = __expf(s);
      sc[h][n] = e;
      psum[h] += e;
    }
  }
  #pragma unroll
  for (int h = 0; h < H; ++h) {
    float v = psum[h];
    #pragma unroll
    for (int d = 32; d >= 1; d >>= 1) v += __shfl_xor(v, d, 64);
    if ((t & 63) == 0) wred[t >> 6][h] = v;
  }
  __syncthreads();
  if (t < H) winv[t] = 1.f / (wred[0][t] + wred[1][t] + wred[2][t] + wred[3][t]);
  __syncthreads();

  // weighted aggregate over neighbors; 2-way row split across half-blocks
  const int part = t >> 7;
  const int tt   = t & 127;
  const int h    = tt >> 5;
  const float* hb = hfeat + (size_t)bbase * HID;
  float acc = 0.f;
  for (int n = part; n < deg; n += 2)
    acc += sc[h][n] * hb[(size_t)nbr[n] * HID + tt];
  if (part == 0) accbuf[tt] = acc;
  __syncthreads();
  if (part == 1)
    conv[(size_t)bi * HID + tt] = (accbuf[tt] + acc) * winv[h] + bias[tt];
}

// ------------- GRU / decoder arg pack -------------
struct Args {
  const float* conv;
  const float* h[3];
  const float* Wu[3]; const float* bu[3];
  const float* Wr[3]; const float* br[3];
  const float* Wc[3]; const float* bc[3];
  const float* R[3];
  float* u[3];
  float* rh[3];
  float* hout[3];            // d_out tail (fp32 h')
  __hip_bfloat16* hb[3];     // bf16 h'
  __hip_bfloat16* gb[3];     // bf16 g = h' @ R
};

// ------------- K3: u,r gates: sigmoid(b + [conv|h] @ W) ; also r*h -------------
__global__ __launch_bounds__(256) void k_gru_ur(Args ga) {
  const int cell = blockIdx.y;
  const int r0   = blockIdx.x * 32;
  const int t    = threadIdx.x;
  const int rg   = t >> 5;              // 0..7 -> 4 rows each
  const int c4   = (t & 31) * 4;        // 4 cols
  __shared__ float As[32][33];
  __shared__ float Wus[32][128];
  __shared__ float Wrs[32][128];
  const float* hc = ga.h[cell];
  const float* Wu = ga.Wu[cell];
  const float* Wr = ga.Wr[cell];
  float au[4][4] = {}; float ar[4][4] = {};
  for (int kt = 0; kt < 8; ++kt) {
    const int k0 = kt * 32;
    const float* Asrc = (kt < 4) ? ga.conv : hc;
    const int koff = k0 & 127;
    {
      const int rr = t >> 3, kk = (t & 7) * 4;
      f32x4 v = *(const f32x4*)&Asrc[(size_t)(r0 + rr) * HID + koff + kk];
      #pragma unroll
      for (int e = 0; e < 4; ++e) As[rr][kk + e] = v[e];
    }
    #pragma unroll
    for (int i = 0; i < 4; ++i) {
      const int idx = t + i * 256;
      const int kk = idx >> 5, cc = (idx & 31) * 4;
      *(f32x4*)&Wus[kk][cc] = *(const f32x4*)&Wu[(size_t)(k0 + kk) * HID + cc];
      *(f32x4*)&Wrs[kk][cc] = *(const f32x4*)&Wr[(size_t)(k0 + kk) * HID + cc];
    }
    __syncthreads();
    for (int kk = 0; kk < 32; ++kk) {
      f32x4 wu = *(const f32x4*)&Wus[kk][c4];
      f32x4 wr = *(const f32x4*)&Wrs[kk][c4];
      #pragma unroll
      for (int i = 0; i < 4; ++i) {
        const float av = As[rg * 4 + i][kk];
        #pragma unroll
        for (int j = 0; j < 4; ++j) { au[i][j] += av * wu[j]; ar[i][j] += av * wr[j]; }
      }
    }
    __syncthreads();
  }
  #pragma unroll
  for (int i = 0; i < 4; ++i) {
    const int row = r0 + rg * 4 + i;
    const int n   = row & (N - 1);
    const float buv = ga.bu[cell][n];
    const float brv = ga.br[cell][n];
    f32x4 hv = *(const f32x4*)&hc[(size_t)row * HID + c4];
    f32x4 uo, ro;
    #pragma unroll
    for (int j = 0; j < 4; ++j) {
      uo[j] = sigmoidf_(au[i][j] + buv);
      ro[j] = sigmoidf_(ar[i][j] + brv) * hv[j];
    }
    *(f32x4*)&ga.u [cell][(size_t)row * HID + c4] = uo;
    *(f32x4*)&ga.rh[cell][(size_t)row * HID + c4] = ro;
  }
}

// ------------- K4: c gate + h' = u*h + (1-u)*tanh(bc + [conv|r*h] @ Wc) -------------
__global__ __launch_bounds__(256) void k_gru_c(Args ga) {
  const int cell = blockIdx.y;
  const int r0   = blockIdx.x * 32;
  const int t    = threadIdx.x;
  const int rg   = t >> 5;
  const int c4   = (t & 31) * 4;
  __shared__ float As[32][33];
  __shared__ float Ws[32][128];
  const float* rhc = ga.rh[cell];
  const float* Wc  = ga.Wc[cell];
  float ac[4][4] = {};
  for (int kt = 0; kt < 8; ++kt) {
    const int k0 = kt * 32;
    const float* Asrc = (kt < 4) ? ga.conv : rhc;
    const int koff = k0 & 127;
    {
      const int rr = t >> 3, kk = (t & 7) * 4;
      f32x4 v = *(const f32x4*)&Asrc[(size_t)(r0 + rr) * HID + koff + kk];
      #pragma unroll
      for (int e = 0; e < 4; ++e) As[rr][kk + e] = v[e];
    }
    #pragma unroll
    for (int i = 0; i < 4; ++i) {
      const int idx = t + i * 256;
      const int kk = idx >> 5, cc = (idx & 31) * 4;
      *(f32x4*)&Ws[kk][cc] = *(const f32x4*)&Wc[(size_t)(k0 + kk) * HID + cc];
    }
    __syncthreads();
    for (int kk = 0; kk < 32; ++kk) {
      f32x4 w = *(const f32x4*)&Ws[kk][c4];
      #pragma unroll
      for (int i = 0; i < 4; ++i) {
        const float av = As[rg * 4 + i][kk];
        #pragma unroll
        for (int j = 0; j < 4; ++j) ac[i][j] += av * w[j];
      }
    }
    __syncthreads();
  }
  #pragma unroll
  for (int i = 0; i < 4; ++i) {
    const int row = r0 + rg * 4 + i;
    const int n   = row & (N - 1);
    const float bcv = ga.bc[cell][n];
    f32x4 uv = *(const f32x4*)&ga.u[cell][(size_t)row * HID + c4];
    f32x4 hv = *(const f32x4*)&ga.h[cell][(size_t)row * HID + c4];
    f32x4 ho;
    #pragma unroll
    for (int j = 0; j < 4; ++j) {
      const float cv = tanhf(ac[i][j] + bcv);
      ho[j] = uv[j] * hv[j] + (1.f - uv[j]) * cv;
    }
    *(f32x4*)&ga.hout[cell][(size_t)row * HID + c4] = ho;
    __hip_bfloat16* hp = ga.hb[cell] + (size_t)row * HID + c4;
    #pragma unroll
    for (int j = 0; j < 4; ++j) hp[j] = __float2bfloat16(ho[j]);
  }
}

// ------------- K5: g = h' @ R  (bf16 out) -------------
__global__ __launch_bounds__(256) void k_g(Args ga) {
  const int cell = blockIdx.y;
  const int r0   = blockIdx.x * 32;
  const int t    = threadIdx.x;
  const int rg   = t >> 5;
  const int c4   = (t & 31) * 4;
  __shared__ float As[32][33];
  __shared__ float Ws[32][128];
  const float* A = ga.hout[cell];
  const float* R = ga.R[cell];
  float ac[4][4] = {};
  for (int kt = 0; kt < 4; ++kt) {
    const int k0 = kt * 32;
    {
      const int rr = t >> 3, kk = (t & 7) * 4;
      f32x4 v = *(const f32x4*)&A[(size_t)(r0 + rr) * HID + k0 + kk];
      #pragma unroll
      for (int e = 0; e < 4; ++e) As[rr][kk + e] = v[e];
    }
    #pragma unroll
    for (int i = 0; i < 4; ++i) {
      const int idx = t + i * 256;
      const int kk = idx >> 5, cc = (idx & 31) * 4;
      *(f32x4*)&Ws[kk][cc] = *(const f32x4*)&R[(size_t)(k0 + kk) * HID + cc];
    }
    __syncthreads();
    for (int kk = 0; kk < 32; ++kk) {
      f32x4 w = *(const f32x4*)&Ws[kk][c4];
      #pragma unroll
      for (int i = 0; i < 4; ++i) {
        const float av = As[rg * 4 + i][kk];
        #pragma unroll
        for (int j = 0; j < 4; ++j) ac[i][j] += av * w[j];
      }
    }
    __syncthreads();
  }
  #pragma unroll
  for (int i = 0; i < 4; ++i) {
    const int row = r0 + rg * 4 + i;
    __hip_bfloat16* gp = ga.gb[cell] + (size_t)row * HID + c4;
    #pragma unroll
    for (int j = 0; j < 4; ++j) gp[j] = __float2bfloat16(ac[i][j]);
  }
}

// ------------- K6: logits[b,i,j,k] = g_k[b,i,:] . h_k[b,j,:]  (bf16 MFMA, NT) -------------
__global__ __launch_bounds__(256) void k_bilinear(
    const __hip_bfloat16* __restrict__ g0, const __hip_bfloat16* __restrict__ g1,
    const __hip_bfloat16* __restrict__ g2, const __hip_bfloat16* __restrict__ h0,
    const __hip_bfloat16* __restrict__ h1, const __hip_bfloat16* __restrict__ h2,
    float* __restrict__ out) {
  const int ti = blockIdx.x, tj = blockIdx.y, b = blockIdx.z;
  const int t = threadIdx.x;
  const int w = t >> 6, l = t & 63;
  const int wi = w >> 1, wj = w & 1;
  const int i_base = ti * 64 + wi * 32;
  const int j_base = tj * 64 + wj * 32;
  const __hip_bfloat16* gbs[3] = {g0, g1, g2};
  const __hip_bfloat16* hbs[3] = {h0, h1, h2};
  const int lr = l & 15;
  const int kb = (l >> 4) * 8;
  f32x4 acc[3][2][2] = {};
  for (int k0 = 0; k0 < HID; k0 += 32) {
    bf16x8 af[3][2], bfr[3][2];
    #pragma unroll
    for (int d = 0; d < 3; ++d) {
      #pragma unroll
      for (int m = 0; m < 2; ++m) {
        af[d][m]  = *(const bf16x8*)&gbs[d][(size_t)(b * N + i_base + m * 16 + lr) * HID + k0 + kb];
        bfr[d][m] = *(const bf16x8*)&hbs[d][(size_t)(b * N + j_base + m * 16 + lr) * HID + k0 + kb];
      }
    }
    #pragma unroll
    for (int d = 0; d < 3; ++d)
      #pragma unroll
      for (int mi = 0; mi < 2; ++mi)
        #pragma unroll
        for (int mj = 0; mj < 2; ++mj)
          acc[d][mi][mj] = __builtin_amdgcn_mfma_f32_16x16x32_bf16(
              af[d][mi], bfr[d][mj], acc[d][mi][mj], 0, 0, 0);
  }
  const int orow = (l >> 4) * 4;
  const int col  = l & 15;
  #pragma unroll
  for (int mi = 0; mi < 2; ++mi)
    #pragma unroll
    for (int mj = 0; mj < 2; ++mj)
      #pragma unroll
      for (int r = 0; r < 4; ++r) {
        const int row = i_base + mi * 16 + orow + r;
        const int cc  = j_base + mj * 16 + col;
        float* p = &out[(((size_t)(b * N + row)) * N + cc) * 3];
        p[0] = acc[0][mi][mj][r];
        p[1] = acc[1][mi][mj][r];
        p[2] = acc[2][mi][mj][r];
      }
}

extern "C" void kernel_launch(void* const* d_in, const int* in_sizes, int n_in,
                              void* d_out, int out_size, void* d_ws, size_t ws_size,
                              hipStream_t stream) {
  (void)in_sizes; (void)n_in; (void)out_size; (void)ws_size;
  const float* x    = (const float*)d_in[0];
  const float* a    = (const float*)d_in[1];
  const float* gk   = (const float*)d_in[5];
  const float* asel = (const float*)d_in[6];
  const float* anei = (const float*)d_in[7];
  const float* bias = (const float*)d_in[8];

  float* ws      = (float*)d_ws;
  float* hfeat   = ws;                                    // BN*HID
  float* sself   = hfeat + (size_t)BN * HID;              // BN*H
  float* sneigh  = sself + (size_t)BN * H;                // BN*H
  float* conv    = sneigh + (size_t)BN * H;               // BN*HID
  float* ubuf    = conv + (size_t)BN * HID;               // 3 * BN*HID
  float* rhbuf   = ubuf + 3 * (size_t)BN * HID;           // 3 * BN*HID
  __hip_bfloat16* bfarea = (__hip_bfloat16*)(rhbuf + 3 * (size_t)BN * HID);

  float* out = (float*)d_out;

  Args ga;
  ga.conv = conv;
  ga.h[0] = (const float*)d_in[2];
  ga.h[1] = (const float*)d_in[3];
  ga.h[2] = (const float*)d_in[4];
  for (int c = 0; c < 3; ++c) {
    const int base = 9 + c * 6;
    ga.Wu[c] = (const float*)d_in[base + 0]; ga.bu[c] = (const float*)d_in[base + 1];
    ga.Wr[c] = (const float*)d_in[base + 2]; ga.br[c] = (const float*)d_in[base + 3];
    ga.Wc[c] = (const float*)d_in[base + 4]; ga.bc[c] = (const float*)d_in[base + 5];
    ga.R[c]  = (const float*)d_in[27 + c];
    ga.u[c]    = ubuf  + (size_t)c * BN * HID;
    ga.rh[c]   = rhbuf + (size_t)c * BN * HID;
    ga.hout[c] = out + LOG_SZ + (size_t)c * BN * HID;
    ga.hb[c]   = bfarea + (size_t)c * BN * HID;
    ga.gb[c]   = bfarea + (size_t)(3 + c) * BN * HID;
  }

  k_feat<<<BN, 128, 0, stream>>>(x, gk, asel, anei, hfeat, sself, sneigh);
  k_attn<<<BN, 256, 0, stream>>>(a, hfeat, sself, sneigh, bias, conv);
  dim3 gg(BN / 32, 3);
  k_gru_ur<<<gg, 256, 0, stream>>>(ga);
  k_gru_c<<<gg, 256, 0, stream>>>(ga);
  k_g<<<gg, 256, 0, stream>>>(ga);
  dim3 g2(N / 64, N / 64, B);
  k_bilinear<<<g2, 256, 0, stream>>>(ga.gb[0], ga.gb[1], ga.gb[2],
                                     ga.hb[0], ga.hb[1], ga.hb[2], out);
}

// Round 2
// 142.025 us; speedup vs baseline: 1.2604x; 1.2604x over previous
//
#include <hip/hip_runtime.h>
#include <hip/hip_bf16.h>

typedef __attribute__((ext_vector_type(4))) float f32x4;
typedef __attribute__((ext_vector_type(8))) short bf16x8;

static constexpr int B   = 2;
static constexpr int N   = 2048;
static constexpr int F   = 64;
static constexpr int H   = 4;
static constexpr int HID = 128;
static constexpr int BN  = B * N;
static constexpr size_t LOG_SZ = (size_t)B * N * N * 3;

__device__ __forceinline__ float sigmoidf_(float x) { return 1.0f / (1.0f + __expf(-x)); }

// ------------- K1: hfeat = x @ gat_kernel ; s_self, s_neigh -------------
__global__ __launch_bounds__(128) void k_feat(
    const float* __restrict__ x, const float* __restrict__ gk,
    const float* __restrict__ asel, const float* __restrict__ anei,
    float* __restrict__ hfeat, float* __restrict__ sself, float* __restrict__ sneigh) {
  const int bn = blockIdx.x;
  const int t  = threadIdx.x;           // 0..127 = h*32+c
  __shared__ float xs[F];
  if (t < F) xs[t] = x[(size_t)bn * F + t];
  __syncthreads();
  float acc = 0.f;
  #pragma unroll 8
  for (int f = 0; f < F; ++f) acc += xs[f] * gk[f * HID + t];
  hfeat[(size_t)bn * HID + t] = acc;
  float ps = acc * asel[t];
  float pn = acc * anei[t];
  #pragma unroll
  for (int d = 16; d >= 1; d >>= 1) {
    ps += __shfl_xor(ps, d, 32);
    pn += __shfl_xor(pn, d, 32);
  }
  if ((t & 31) == 0) {
    sself [bn * H + (t >> 5)] = ps;
    sneigh[bn * H + (t >> 5)] = pn;
  }
}

// ------------- K2: sparse GAT attention — one wave per row, sync-free -------------
__global__ __launch_bounds__(256) void k_attn(
    const float* __restrict__ a, const float* __restrict__ hfeat,
    const float* __restrict__ sself, const float* __restrict__ sneigh,
    const float* __restrict__ bias, float* __restrict__ conv) {
  const int wv   = threadIdx.x >> 6;    // wave 0..3
  const int lane = threadIdx.x & 63;
  const int bi   = blockIdx.x * 4 + wv; // global row (b*N+i)
  const int bbase = bi & ~(N - 1);      // b*N
  __shared__ int   nbr[4][256];
  __shared__ float wts[4][256][4];
  int*   nb       = nbr[wv];
  float (*wt)[4]  = wts[wv];

  const float si0 = sself[bi * H + 0];
  const float si1 = sself[bi * H + 1];
  const float si2 = sself[bi * H + 2];
  const float si3 = sself[bi * H + 3];
  float den0 = 0.f, den1 = 0.f, den2 = 0.f, den3 = 0.f;
  float acc0 = 0.f, acc1 = 0.f;
  const unsigned long long lmlt = ((unsigned long long)1 << lane) - 1ull;
  const float* arow = a + (size_t)bi * N;
  const float* hb   = hfeat + (size_t)bbase * HID;
  const float* snb  = sneigh + (size_t)bbase * H;
  const int h0 = lane >> 5;             // head of channel `lane` (0/1)
  int num = 0;

  auto flush = [&]() {
    asm volatile("s_waitcnt lgkmcnt(0)" ::: "memory");  // nb writes visible
    // per-neighbor weights (lane-strided) + lane-partial denominators
    for (int n = lane; n < num; n += 64) {
      const int j = nb[n];
      f32x4 sn = *(const f32x4*)&snb[(size_t)j * H];
      float s0 = si0 + sn[0]; s0 = (s0 > 0.f) ? s0 : 0.2f * s0;
      float s1 = si1 + sn[1]; s1 = (s1 > 0.f) ? s1 : 0.2f * s1;
      float s2 = si2 + sn[2]; s2 = (s2 > 0.f) ? s2 : 0.2f * s2;
      float s3 = si3 + sn[3]; s3 = (s3 > 0.f) ? s3 : 0.2f * s3;
      float w0 = __expf(s0), w1 = __expf(s1), w2 = __expf(s2), w3 = __expf(s3);
      wt[n][0] = w0; wt[n][1] = w1; wt[n][2] = w2; wt[n][3] = w3;
      den0 += w0; den1 += w1; den2 += w2; den3 += w3;
    }
    asm volatile("s_waitcnt lgkmcnt(0)" ::: "memory");  // wt writes visible
    // aggregate: all lanes cooperate, 2 channels each
    #pragma unroll 2
    for (int n = 0; n < num; ++n) {
      const int j  = nb[n];
      const float wA = wt[n][h0];
      const float wB = wt[n][h0 + 2];
      const float* hr = hb + (size_t)j * HID;
      acc0 += wA * hr[lane];
      acc1 += wB * hr[lane + 64];
    }
    asm volatile("s_waitcnt lgkmcnt(0)" ::: "memory");  // reads done before reuse
    num = 0;
  };

  for (int jb = 0; jb < N; jb += 256) {
    f32x4 av = *(const f32x4*)&arow[jb + lane * 4];
    #pragma unroll
    for (int e = 0; e < 4; ++e) {
      const unsigned long long m = __ballot(av[e] > 0.5f);
      if (av[e] > 0.5f) {
        const int pos = num + __popcll(m & lmlt);
        nb[pos] = jb + lane * 4 + e;
      }
      num += __popcll(m);
      if (num > 192) flush();           // wave-uniform
    }
  }
  if (num > 0) flush();

  #pragma unroll
  for (int d = 32; d >= 1; d >>= 1) {
    den0 += __shfl_xor(den0, d, 64);
    den1 += __shfl_xor(den1, d, 64);
    den2 += __shfl_xor(den2, d, 64);
    den3 += __shfl_xor(den3, d, 64);
  }
  const float dA = h0 ? den1 : den0;
  const float dB = h0 ? den3 : den2;
  conv[(size_t)bi * HID + lane]      = acc0 / dA + bias[lane];
  conv[(size_t)bi * HID + 64 + lane] = acc1 / dB + bias[64 + lane];
}

// ------------- GRU / decoder arg pack -------------
struct Args {
  const float* conv;
  const float* h[3];
  const float* Wu[3]; const float* bu[3];
  const float* Wr[3]; const float* br[3];
  const float* Wc[3]; const float* bc[3];
  const float* R[3];
  float* u[3];
  float* rh[3];
  float* hout[3];            // d_out tail (fp32 h')
  __hip_bfloat16* hb[3];     // bf16 h'
  __hip_bfloat16* gb[3];     // bf16 g = h' @ R
};

// ------------- K3: u,r gates: sigmoid(b + [conv|h] @ W) ; also r*h -------------
__global__ __launch_bounds__(256) void k_gru_ur(Args ga) {
  const int cell = blockIdx.y;
  const int r0   = blockIdx.x * 32;
  const int t    = threadIdx.x;
  const int rg   = t >> 5;              // 0..7 -> 4 rows each
  const int c4   = (t & 31) * 4;        // 4 cols
  __shared__ float As[32][33];
  __shared__ float Wus[32][128];
  __shared__ float Wrs[32][128];
  const float* hc = ga.h[cell];
  const float* Wu = ga.Wu[cell];
  const float* Wr = ga.Wr[cell];
  float au[4][4] = {}; float ar[4][4] = {};
  for (int kt = 0; kt < 8; ++kt) {
    const int k0 = kt * 32;
    const float* Asrc = (kt < 4) ? ga.conv : hc;
    const int koff = k0 & 127;
    {
      const int rr = t >> 3, kk = (t & 7) * 4;
      f32x4 v = *(const f32x4*)&Asrc[(size_t)(r0 + rr) * HID + koff + kk];
      #pragma unroll
      for (int e = 0; e < 4; ++e) As[rr][kk + e] = v[e];
    }
    #pragma unroll
    for (int i = 0; i < 4; ++i) {
      const int idx = t + i * 256;
      const int kk = idx >> 5, cc = (idx & 31) * 4;
      *(f32x4*)&Wus[kk][cc] = *(const f32x4*)&Wu[(size_t)(k0 + kk) * HID + cc];
      *(f32x4*)&Wrs[kk][cc] = *(const f32x4*)&Wr[(size_t)(k0 + kk) * HID + cc];
    }
    __syncthreads();
    for (int kk = 0; kk < 32; ++kk) {
      f32x4 wu = *(const f32x4*)&Wus[kk][c4];
      f32x4 wr = *(const f32x4*)&Wrs[kk][c4];
      #pragma unroll
      for (int i = 0; i < 4; ++i) {
        const float av = As[rg * 4 + i][kk];
        #pragma unroll
        for (int j = 0; j < 4; ++j) { au[i][j] += av * wu[j]; ar[i][j] += av * wr[j]; }
      }
    }
    __syncthreads();
  }
  #pragma unroll
  for (int i = 0; i < 4; ++i) {
    const int row = r0 + rg * 4 + i;
    const int n   = row & (N - 1);
    const float buv = ga.bu[cell][n];
    const float brv = ga.br[cell][n];
    f32x4 hv = *(const f32x4*)&hc[(size_t)row * HID + c4];
    f32x4 uo, ro;
    #pragma unroll
    for (int j = 0; j < 4; ++j) {
      uo[j] = sigmoidf_(au[i][j] + buv);
      ro[j] = sigmoidf_(ar[i][j] + brv) * hv[j];
    }
    *(f32x4*)&ga.u [cell][(size_t)row * HID + c4] = uo;
    *(f32x4*)&ga.rh[cell][(size_t)row * HID + c4] = ro;
  }
}

// ------------- K4: c gate + h' = u*h + (1-u)*tanh(bc + [conv|r*h] @ Wc) -------------
__global__ __launch_bounds__(256) void k_gru_c(Args ga) {
  const int cell = blockIdx.y;
  const int r0   = blockIdx.x * 32;
  const int t    = threadIdx.x;
  const int rg   = t >> 5;
  const int c4   = (t & 31) * 4;
  __shared__ float As[32][33];
  __shared__ float Ws[32][128];
  const float* rhc = ga.rh[cell];
  const float* Wc  = ga.Wc[cell];
  float ac[4][4] = {};
  for (int kt = 0; kt < 8; ++kt) {
    const int k0 = kt * 32;
    const float* Asrc = (kt < 4) ? ga.conv : rhc;
    const int koff = k0 & 127;
    {
      const int rr = t >> 3, kk = (t & 7) * 4;
      f32x4 v = *(const f32x4*)&Asrc[(size_t)(r0 + rr) * HID + koff + kk];
      #pragma unroll
      for (int e = 0; e < 4; ++e) As[rr][kk + e] = v[e];
    }
    #pragma unroll
    for (int i = 0; i < 4; ++i) {
      const int idx = t + i * 256;
      const int kk = idx >> 5, cc = (idx & 31) * 4;
      *(f32x4*)&Ws[kk][cc] = *(const f32x4*)&Wc[(size_t)(k0 + kk) * HID + cc];
    }
    __syncthreads();
    for (int kk = 0; kk < 32; ++kk) {
      f32x4 w = *(const f32x4*)&Ws[kk][c4];
      #pragma unroll
      for (int i = 0; i < 4; ++i) {
        const float av = As[rg * 4 + i][kk];
        #pragma unroll
        for (int j = 0; j < 4; ++j) ac[i][j] += av * w[j];
      }
    }
    __syncthreads();
  }
  #pragma unroll
  for (int i = 0; i < 4; ++i) {
    const int row = r0 + rg * 4 + i;
    const int n   = row & (N - 1);
    const float bcv = ga.bc[cell][n];
    f32x4 uv = *(const f32x4*)&ga.u[cell][(size_t)row * HID + c4];
    f32x4 hv = *(const f32x4*)&ga.h[cell][(size_t)row * HID + c4];
    f32x4 ho;
    #pragma unroll
    for (int j = 0; j < 4; ++j) {
      const float cv = tanhf(ac[i][j] + bcv);
      ho[j] = uv[j] * hv[j] + (1.f - uv[j]) * cv;
    }
    *(f32x4*)&ga.hout[cell][(size_t)row * HID + c4] = ho;
    __hip_bfloat16* hp = ga.hb[cell] + (size_t)row * HID + c4;
    #pragma unroll
    for (int j = 0; j < 4; ++j) hp[j] = __float2bfloat16(ho[j]);
  }
}

// ------------- K5: g = h' @ R  (bf16 out) -------------
__global__ __launch_bounds__(256) void k_g(Args ga) {
  const int cell = blockIdx.y;
  const int r0   = blockIdx.x * 32;
  const int t    = threadIdx.x;
  const int rg   = t >> 5;
  const int c4   = (t & 31) * 4;
  __shared__ float As[32][33];
  __shared__ float Ws[32][128];
  const float* A = ga.hout[cell];
  const float* R = ga.R[cell];
  float ac[4][4] = {};
  for (int kt = 0; kt < 4; ++kt) {
    const int k0 = kt * 32;
    {
      const int rr = t >> 3, kk = (t & 7) * 4;
      f32x4 v = *(const f32x4*)&A[(size_t)(r0 + rr) * HID + k0 + kk];
      #pragma unroll
      for (int e = 0; e < 4; ++e) As[rr][kk + e] = v[e];
    }
    #pragma unroll
    for (int i = 0; i < 4; ++i) {
      const int idx = t + i * 256;
      const int kk = idx >> 5, cc = (idx & 31) * 4;
      *(f32x4*)&Ws[kk][cc] = *(const f32x4*)&R[(size_t)(k0 + kk) * HID + cc];
    }
    __syncthreads();
    for (int kk = 0; kk < 32; ++kk) {
      f32x4 w = *(const f32x4*)&Ws[kk][c4];
      #pragma unroll
      for (int i = 0; i < 4; ++i) {
        const float av = As[rg * 4 + i][kk];
        #pragma unroll
        for (int j = 0; j < 4; ++j) ac[i][j] += av * w[j];
      }
    }
    __syncthreads();
  }
  #pragma unroll
  for (int i = 0; i < 4; ++i) {
    const int row = r0 + rg * 4 + i;
    __hip_bfloat16* gp = ga.gb[cell] + (size_t)row * HID + c4;
    #pragma unroll
    for (int j = 0; j < 4; ++j) gp[j] = __float2bfloat16(ac[i][j]);
  }
}

// ------------- K6: logits[b,i,j,k] = g_k[b,i,:] . h_k[b,j,:]  (bf16 MFMA, NT) -------------
__global__ __launch_bounds__(256) void k_bilinear(
    const __hip_bfloat16* __restrict__ g0, const __hip_bfloat16* __restrict__ g1,
    const __hip_bfloat16* __restrict__ g2, const __hip_bfloat16* __restrict__ h0,
    const __hip_bfloat16* __restrict__ h1, const __hip_bfloat16* __restrict__ h2,
    float* __restrict__ out) {
  const int ti = blockIdx.x, tj = blockIdx.y, b = blockIdx.z;
  const int t = threadIdx.x;
  const int w = t >> 6, l = t & 63;
  const int wi = w >> 1, wj = w & 1;
  const int i_base = ti * 64 + wi * 32;
  const int j_base = tj * 64 + wj * 32;
  const __hip_bfloat16* gbs[3] = {g0, g1, g2};
  const __hip_bfloat16* hbs[3] = {h0, h1, h2};
  const int lr = l & 15;
  const int kb = (l >> 4) * 8;
  f32x4 acc[3][2][2] = {};
  for (int k0 = 0; k0 < HID; k0 += 32) {
    bf16x8 af[3][2], bfr[3][2];
    #pragma unroll
    for (int d = 0; d < 3; ++d) {
      #pragma unroll
      for (int m = 0; m < 2; ++m) {
        af[d][m]  = *(const bf16x8*)&gbs[d][(size_t)(b * N + i_base + m * 16 + lr) * HID + k0 + kb];
        bfr[d][m] = *(const bf16x8*)&hbs[d][(size_t)(b * N + j_base + m * 16 + lr) * HID + k0 + kb];
      }
    }
    #pragma unroll
    for (int d = 0; d < 3; ++d)
      #pragma unroll
      for (int mi = 0; mi < 2; ++mi)
        #pragma unroll
        for (int mj = 0; mj < 2; ++mj)
          acc[d][mi][mj] = __builtin_amdgcn_mfma_f32_16x16x32_bf16(
              af[d][mi], bfr[d][mj], acc[d][mi][mj], 0, 0, 0);
  }
  const int orow = (l >> 4) * 4;
  const int col  = l & 15;
  #pragma unroll
  for (int mi = 0; mi < 2; ++mi)
    #pragma unroll
    for (int mj = 0; mj < 2; ++mj)
      #pragma unroll
      for (int r = 0; r < 4; ++r) {
        const int row = i_base + mi * 16 + orow + r;
        const int cc  = j_base + mj * 16 + col;
        float* p = &out[(((size_t)(b * N + row)) * N + cc) * 3];
        p[0] = acc[0][mi][mj][r];
        p[1] = acc[1][mi][mj][r];
        p[2] = acc[2][mi][mj][r];
      }
}

extern "C" void kernel_launch(void* const* d_in, const int* in_sizes, int n_in,
                              void* d_out, int out_size, void* d_ws, size_t ws_size,
                              hipStream_t stream) {
  (void)in_sizes; (void)n_in; (void)out_size; (void)ws_size;
  const float* x    = (const float*)d_in[0];
  const float* a    = (const float*)d_in[1];
  const float* gk   = (const float*)d_in[5];
  const float* asel = (const float*)d_in[6];
  const float* anei = (const float*)d_in[7];
  const float* bias = (const float*)d_in[8];

  float* ws      = (float*)d_ws;
  float* hfeat   = ws;                                    // BN*HID
  float* sself   = hfeat + (size_t)BN * HID;              // BN*H
  float* sneigh  = sself + (size_t)BN * H;                // BN*H
  float* conv    = sneigh + (size_t)BN * H;               // BN*HID
  float* ubuf    = conv + (size_t)BN * HID;               // 3 * BN*HID
  float* rhbuf   = ubuf + 3 * (size_t)BN * HID;           // 3 * BN*HID
  __hip_bfloat16* bfarea = (__hip_bfloat16*)(rhbuf + 3 * (size_t)BN * HID);

  float* out = (float*)d_out;

  Args ga;
  ga.conv = conv;
  ga.h[0] = (const float*)d_in[2];
  ga.h[1] = (const float*)d_in[3];
  ga.h[2] = (const float*)d_in[4];
  for (int c = 0; c < 3; ++c) {
    const int base = 9 + c * 6;
    ga.Wu[c] = (const float*)d_in[base + 0]; ga.bu[c] = (const float*)d_in[base + 1];
    ga.Wr[c] = (const float*)d_in[base + 2]; ga.br[c] = (const float*)d_in[base + 3];
    ga.Wc[c] = (const float*)d_in[base + 4]; ga.bc[c] = (const float*)d_in[base + 5];
    ga.R[c]  = (const float*)d_in[27 + c];
    ga.u[c]    = ubuf  + (size_t)c * BN * HID;
    ga.rh[c]   = rhbuf + (size_t)c * BN * HID;
    ga.hout[c] = out + LOG_SZ + (size_t)c * BN * HID;
    ga.hb[c]   = bfarea + (size_t)c * BN * HID;
    ga.gb[c]   = bfarea + (size_t)(3 + c) * BN * HID;
  }

  k_feat<<<BN, 128, 0, stream>>>(x, gk, asel, anei, hfeat, sself, sneigh);
  k_attn<<<BN / 4, 256, 0, stream>>>(a, hfeat, sself, sneigh, bias, conv);
  dim3 gg(BN / 32, 3);
  k_gru_ur<<<gg, 256, 0, stream>>>(ga);
  k_gru_c<<<gg, 256, 0, stream>>>(ga);
  k_g<<<gg, 256, 0, stream>>>(ga);
  dim3 g2(N / 64, N / 64, B);
  k_bilinear<<<g2, 256, 0, stream>>>(ga.gb[0], ga.gb[1], ga.gb[2],
                                     ga.hb[0], ga.hb[1], ga.hb[2], out);
}